// Round 11
// baseline (240.740 us; speedup 1.0000x reference)
//
#include <hip/hip_runtime.h>
#include <hip/hip_bf16.h>
#include <stdint.h>

// Causal MHA, B=8 S=2048 E=768 N=12 H=64. fp32 in/out, bf16 MFMA compute.
// prep packs x, W_QKV, W_O fragment-major -> qkv/out gemms are barrier-free
// direct register GEMMs (R7 config). qkv writes K and V directly in
// MFMA-fragment-major (Kp permuted, Vp plain) -> attn is LDS-free: Q in regs
// (64 q-rows/wave = 2x K/V reuse, 256 B/MFMA), K/V as contiguous 1KB
// wave-loads with a 2-set prefetch pipeline. attn writes Z fragment-major.

#define B_ 8
#define S_ 2048
#define E_ 768
#define NHEADS 12
#define HD 64
#define BS (B_*S_)        // 16384
#define NHD (NHEADS*HD)   // 768

typedef short bf16x8 __attribute__((ext_vector_type(8)));   // 8 bf16 = 4 VGPR
typedef short bf16x4 __attribute__((ext_vector_type(4)));
typedef float f32x4  __attribute__((ext_vector_type(4)));   // MFMA C/D frag
typedef __hip_bfloat16 bf16;

__device__ __forceinline__ f32x4 mfma16(bf16x8 a, bf16x8 b, f32x4 c) {
    return __builtin_amdgcn_mfma_f32_16x16x32_bf16(a, b, c, 0, 0, 0);
}
__device__ __forceinline__ bf16x8 ld8(const bf16* p) {
    return *reinterpret_cast<const bf16x8*>(p);
}
__device__ __forceinline__ bf16x8 pack8(f32x4 a, f32x4 b) {
    union { bf16x8 v; __hip_bfloat162 h[4]; } u;
    u.h[0] = __float22bfloat162_rn(make_float2(a[0], a[1]));
    u.h[1] = __float22bfloat162_rn(make_float2(a[2], a[3]));
    u.h[2] = __float22bfloat162_rn(make_float2(b[0], b[1]));
    u.h[3] = __float22bfloat162_rn(make_float2(b[2], b[3]));
    return u.v;
}

// Fragment-major packed layout for an [R][768] row-major matrix:
// frag (rg = r/16, kc = k/32) occupies 512 elems at (rg*24 + kc)*512;
// element (rl=r%16, kq=(k%32)/8, e=k%8) sits at (kq*16 + rl)*8 + e.
// One ld8 at frag_base + lane*8 is exactly the 16x16x32 MFMA operand.

// ---------------- prep: pack x, W_QKV, W_O fragment-major --------------------
__global__ __launch_bounds__(256) void prep_kernel(
    const float* __restrict__ x,  const float* __restrict__ Wq,
    const float* __restrict__ Wk, const float* __restrict__ Wv,
    const float* __restrict__ Wo,
    bf16* __restrict__ xp,  bf16* __restrict__ WTp, bf16* __restrict__ WoTp)
{
    const int tid = blockIdx.x * 256 + threadIdx.x;
    const int nth = gridDim.x * 256;

    // x [16384][768] f32 -> packed bf16
    for (int c = tid; c < BS*E_/8; c += nth) {
        const int r  = c / 96;               // row
        const int k8 = (c - r*96) * 8;       // k start (multiple of 8)
        const float4 f0 = *reinterpret_cast<const float4*>(x + (size_t)r*E_ + k8);
        const float4 f1 = *reinterpret_cast<const float4*>(x + (size_t)r*E_ + k8 + 4);
        union { bf16x8 v; __hip_bfloat162 h[4]; } u;
        u.h[0] = __float22bfloat162_rn(make_float2(f0.x, f0.y));
        u.h[1] = __float22bfloat162_rn(make_float2(f0.z, f0.w));
        u.h[2] = __float22bfloat162_rn(make_float2(f1.x, f1.y));
        u.h[3] = __float22bfloat162_rn(make_float2(f1.z, f1.w));
        const size_t dst = (size_t)((r>>4)*24 + (k8>>5))*512
                         + (size_t)((((k8>>3)&3)<<4) + (r&15))*8;
        *reinterpret_cast<bf16x8*>(xp + dst) = u.v;
    }

    // W_{Q,K,V}[n][e][h] -> packed B rows r = mat*768 + (n*64+h), k = e
    for (int c2 = tid; c2 < NHD*96; c2 += nth) {
        const int r  = c2 / 96;              // (n,h) output-col index 0..767
        const int e8 = (c2 - r*96) * 8;      // k start
        const int n = r >> 6, h = r & 63;
        const float* sq = Wq + (size_t)(n*E_ + e8)*HD + h;
        const float* sk = Wk + (size_t)(n*E_ + e8)*HD + h;
        const float* sv = Wv + (size_t)(n*E_ + e8)*HD + h;
        union { bf16x8 v; bf16 el[8]; } uq, uk, uv;
        #pragma unroll
        for (int j = 0; j < 8; ++j) {
            uq.el[j] = __float2bfloat16(sq[(size_t)j*HD]);
            uk.el[j] = __float2bfloat16(sk[(size_t)j*HD]);
            uv.el[j] = __float2bfloat16(sv[(size_t)j*HD]);
        }
        const size_t sub = (size_t)(e8>>5)*512
                         + (size_t)((((e8>>3)&3)<<4) + (r&15))*8;
        const size_t rg  = (size_t)(r>>4);   // within-matrix row-group
        *reinterpret_cast<bf16x8*>(WTp + ((0*48 + rg)*24)*512 + sub) = uq.v;
        *reinterpret_cast<bf16x8*>(WTp + ((1*48 + rg)*24)*512 + sub) = uk.v;
        *reinterpret_cast<bf16x8*>(WTp + ((2*48 + rg)*24)*512 + sub) = uv.v;
    }

    // Wo flat[c][e] -> packed B^T rows e (0..767), k = c (0..767)
    for (int c3 = tid; c3 < E_*96; c3 += nth) {
        const int e  = c3 / 96;
        const int c8 = (c3 - e*96) * 8;
        union { bf16x8 v; bf16 el[8]; } u;
        #pragma unroll
        for (int j = 0; j < 8; ++j)
            u.el[j] = __float2bfloat16(Wo[(size_t)(c8 + j)*E_ + e]);
        const size_t dst = (size_t)((e>>4)*24 + (c8>>5))*512
                         + (size_t)((((c8>>3)&3)<<4) + (e&15))*8;
        *reinterpret_cast<bf16x8*>(WoTp + dst) = u.v;
    }
}

// ========== direct packed GEMM, explicit 2-deep prefetch pipeline ============
// R7 config (best measured): launch_bounds(256,2), VGPR~100, MfmaUtil ~28% =
// the operand-delivery roofline for a 64x64 wave tile (~500 B/MFMA).

#define LOAD_A(dst, base, kt, NM)                                                 \
    _Pragma("unroll") for (int m = 0; m < NM; ++m)                                \
    _Pragma("unroll") for (int ks = 0; ks < 2; ++ks)                              \
        dst[m][ks] = ld8((base) + ((size_t)m*24 + (kt)*2 + ks)*512);

#define MFMA_BLK(af, bfv, NM, NN)                                                 \
    _Pragma("unroll") for (int ks = 0; ks < 2; ++ks)                              \
    _Pragma("unroll") for (int m = 0; m < NM; ++m)                                \
    _Pragma("unroll") for (int n = 0; n < NN; ++n)                                \
        acc[m][n] = mfma16(af[m][ks], bfv[n][ks], acc[m][n]);

#define DIRECT_PIPE_BODY(Abase, Bbase, NM, NN)                                    \
    f32x4 acc[NM][NN];                                                            \
    _Pragma("unroll") for (int mf = 0; mf < NM; ++mf)                             \
    _Pragma("unroll") for (int nf = 0; nf < NN; ++nf)                             \
        acc[mf][nf] = (f32x4){0.f, 0.f, 0.f, 0.f};                                \
    bf16x8 a0[NM][2], b0[NN][2], a1[NM][2], b1[NN][2];                            \
    LOAD_A(a0, Abase, 0, NM); LOAD_A(b0, Bbase, 0, NN);                           \
    _Pragma("unroll 1")                                                           \
    for (int kk = 0; kk < 6; ++kk) {                                              \
        const int ktA = 2*kk + 1;                                                 \
        const int ktB = (2*kk + 2 < 12) ? 2*kk + 2 : 11;                          \
        LOAD_A(a1, Abase, ktA, NM); LOAD_A(b1, Bbase, ktA, NN);                   \
        __builtin_amdgcn_sched_barrier(0);                                        \
        MFMA_BLK(a0, b0, NM, NN);                                                 \
        LOAD_A(a0, Abase, ktB, NM); LOAD_A(b0, Bbase, ktB, NN);                   \
        __builtin_amdgcn_sched_barrier(0);                                        \
        MFMA_BLK(a1, b1, NM, NN);                                                 \
    }

// ---------------- QKV projection: 128x128 blocks, wave tile 64x64 ------------
// Q -> Qb [B][N][S][H] (pre-scaled); K -> Kp packed frags (permuted so the
// QK^T C-row maps to kv = kvbase + quad*8 + bg*4 + r); V -> Vp packed frags.
// Kp/Vp: per head 64 kv-groups(32) x 4 frags x 512 elems = 256 KB.
__global__ __launch_bounds__(256, 2) void qkv_gemm_p(
    const bf16* __restrict__ xp, const bf16* __restrict__ WTp,
    const float* __restrict__ bq, const float* __restrict__ bk, const float* __restrict__ bv,
    bf16* __restrict__ Qb, bf16* __restrict__ Kp, bf16* __restrict__ Vp)
{
    const int tm = blockIdx.x, tn = blockIdx.y;   // (128, 18)
    const int lane = threadIdx.x & 63;
    const int w    = threadIdx.x >> 6;            // 0..3
    const int wm = w >> 1, wn = w & 1;
    const int l16 = lane & 15, quad = lane >> 4;
    const bf16* Abase = xp  + ((size_t)(tm*8 + wm*4)*24)*512 + lane*8;
    const bf16* Bbase = WTp + ((size_t)(tn*8 + wn*4)*24)*512 + lane*8;

    DIRECT_PIPE_BODY(Abase, Bbase, 4, 4);

    const int mat = tn / 6;                  // 0=Q 1=K 2=V
    const int cloc0 = (tn - mat*6)*128 + wn*64;
    const float* bias = (mat==0) ? bq : (mat==1) ? bk : bv;
    const float scale = (mat==0) ? 0.125f * 1.44269504088896340736f : 1.0f;
    #pragma unroll
    for (int nf = 0; nf < 4; ++nf) {
        const int col = cloc0 + nf*16 + l16;       // 0..767 within matrix
        const int hn = col >> 6, h = col & 63;
        const float bb = bias[col];
        #pragma unroll
        for (int mf = 0; mf < 4; ++mf) {
            const int row = tm*128 + wm*64 + mf*16 + quad*4;
            const int bi = row >> 11;              // / S_
            const int s  = row & (S_-1);
            const size_t headbase = (size_t)(bi*NHEADS + hn)*256*512;
            if (mat == 0) {                        // Q -> [B][N][S][H] scaled
                bf16* d = Qb + ((size_t)(bi*NHEADS + hn)*S_ + s)*HD + h;
                #pragma unroll
                for (int r = 0; r < 4; ++r)
                    d[(size_t)r*HD] = __float2bfloat16((acc[mf][nf][r] + bb)*scale);
            } else if (mat == 1) {                 // K -> Kp permuted frags
                const int hf = h >> 5, kq = (h >> 3) & 3, e = h & 7;
                #pragma unroll
                for (int r = 0; r < 4; ++r) {
                    const int sr = s + r;
                    const int gg = sr >> 5, kv5 = sr & 31;
                    const int bg = (kv5 >> 2) & 1;
                    const int rl = ((kv5 >> 3) << 2) | (kv5 & 3);
                    Kp[headbase + (size_t)(gg*4 + bg*2 + hf)*512 + (kq*16 + rl)*8 + e]
                        = __float2bfloat16(acc[mf][nf][r] + bb);
                }
            } else {                               // V -> Vp plain frags
                const int dg = (h >> 4) & 3;       // d row-group within head
                const int rl = h & 15;             // = l16
                const int gg = s >> 5;
                const int kq = (s >> 3) & 3;
                const int e0 = s & 7;              // 0 or 4; r consecutive
                union { bf16x4 v; bf16 e[4]; } u;
                #pragma unroll
                for (int r = 0; r < 4; ++r) u.e[r] = __float2bfloat16(acc[mf][nf][r] + bb);
                bf16* d = Vp + headbase + (size_t)(gg*4 + dg)*512 + (kq*16 + rl)*8 + e0;
                *reinterpret_cast<bf16x4*>(d) = u.v;   // 8B aligned
            }
        }
    }
}

// ---------------- output projection: 128x96 blocks, wave tile 64x48 ----------
__global__ __launch_bounds__(256, 2) void out_gemm_p(
    const bf16* __restrict__ Zp, const bf16* __restrict__ WoTp,
    const float* __restrict__ bo, float* __restrict__ out)
{
    const int tm = blockIdx.x, tn = blockIdx.y;   // (128, 8)
    const int lane = threadIdx.x & 63;
    const int w    = threadIdx.x >> 6;
    const int wm = w >> 1, wn = w & 1;
    const int l16 = lane & 15, quad = lane >> 4;
    const bf16* Abase = Zp   + ((size_t)(tm*8 + wm*4)*24)*512 + lane*8;
    const bf16* Bbase = WoTp + ((size_t)(tn*6 + wn*3)*24)*512 + lane*8;

    DIRECT_PIPE_BODY(Abase, Bbase, 4, 3);

    #pragma unroll
    for (int nf = 0; nf < 3; ++nf) {
        const int col = tn*96 + wn*48 + nf*16 + l16;
        const float bb = bo[col];
        #pragma unroll
        for (int mf = 0; mf < 4; ++mf) {
            const int row = tm*128 + wm*64 + mf*16 + quad*4;
            float* d = out + (size_t)row*E_ + col;
            #pragma unroll
            for (int r = 0; r < 4; ++r)
                d[(size_t)r*E_] = acc[mf][nf][r] + bb;
        }
    }
}

// ---------------- flash attention: LDS-free, 64 q-rows/wave ------------------
// 4 independent waves/block (no barriers, no LDS): waves 0-1 -> near qblk,
// waves 2-3 -> far qblk (causal pairing, uniform block work). Each wave holds
// 64 q-rows in regs (bqf[4][2]) so every K/V frag read feeds 64 MFMAs
// (256 B/MFMA, half of the old LDS path). K/V frags are contiguous 1KB
// wave-loads from Kp/Vp; 2-set prefetch pipeline + sched_barrier pinning.
__global__ __launch_bounds__(256, 2) void attn_kernel(
    const bf16* __restrict__ Qb, const bf16* __restrict__ Kp,
    const bf16* __restrict__ Vp, bf16* __restrict__ Zp)
{
    const int id = blockIdx.x;
    const int bx = id / 96;                  // 0..7
    const int hc = id - bx*96;
    const int hn = hc % NHEADS, b = hc / NHEADS;
    const int w    = threadIdx.x >> 6;       // 0..3
    const int lane = threadIdx.x & 63;
    const int l16 = lane & 15, quad = lane >> 4;
    const size_t bn = (size_t)b*NHEADS + hn;

    const int qblk = (w >> 1) ? (15 - bx) : bx;
    const int wsub = w & 1;
    const int qbase = qblk*128 + wsub*64;
    const int jmax  = 2*(2*qblk + wsub) + 1;   // last (kt,c) index; always odd

    const bf16* Qbase = Qb + bn*(size_t)S_*HD;
    const bf16* Kh = Kp + bn*(size_t)256*512;
    const bf16* Vh = Vp + bn*(size_t)256*512;

    bf16x8 bqf[4][2];
    #pragma unroll
    for (int qi = 0; qi < 4; ++qi)
        #pragma unroll
        for (int hf = 0; hf < 2; ++hf)
            bqf[qi][hf] = ld8(Qbase + (size_t)(qbase + qi*16 + l16)*HD + hf*32 + quad*8);

    f32x4 acc[4][4];
    #pragma unroll
    for (int qi = 0; qi < 4; ++qi)
        #pragma unroll
        for (int ht = 0; ht < 4; ++ht) acc[qi][ht] = (f32x4){0.f,0.f,0.f,0.f};
    float lsum[4] = {0.f, 0.f, 0.f, 0.f};

#define LD_KV(ks, vs, gj) do {                                                    \
    _Pragma("unroll") for (int f = 0; f < 4; ++f)                                 \
        ks[f] = ld8(Kh + ((size_t)(gj)*4 + f)*512 + lane*8);                      \
    _Pragma("unroll") for (int f = 0; f < 4; ++f)                                 \
        vs[f] = ld8(Vh + ((size_t)(gj)*4 + f)*512 + lane*8);                      \
} while (0)

#define ATT_COMPUTE(ks, vs, j) do {                                               \
    const int kvbase = (j) * 32;                                                  \
    const bool diag = (kvbase + 31 > qbase);                                      \
    _Pragma("unroll")                                                             \
    for (int qi = 0; qi < 4; ++qi) {                                              \
        f32x4 s0 = (f32x4){0.f,0.f,0.f,0.f};                                      \
        s0 = mfma16(ks[0], bqf[qi][0], s0);                                       \
        s0 = mfma16(ks[1], bqf[qi][1], s0);                                       \
        f32x4 s1 = (f32x4){0.f,0.f,0.f,0.f};                                      \
        s1 = mfma16(ks[2], bqf[qi][0], s1);                                       \
        s1 = mfma16(ks[3], bqf[qi][1], s1);                                       \
        if (diag) {                                                               \
            const int q   = qbase + qi*16 + l16;                                  \
            const int kb0 = kvbase + quad*8;                                      \
            _Pragma("unroll") for (int r = 0; r < 4; ++r) {                       \
                s0[r] = (kb0 + r     > q) ? -1e30f : s0[r];                       \
                s1[r] = (kb0 + 4 + r > q) ? -1e30f : s1[r];                       \
            }                                                                     \
        }                                                                         \
        float ls = 0.f;                                                           \
        _Pragma("unroll") for (int r = 0; r < 4; ++r) {                           \
            s0[r] = __builtin_amdgcn_exp2f(s0[r]);                                \
            s1[r] = __builtin_amdgcn_exp2f(s1[r]);                                \
            ls += s0[r] + s1[r];                                                  \
        }                                                                         \
        lsum[qi] += ls;                                                           \
        const bf16x8 pf = pack8(s0, s1);                                          \
        _Pragma("unroll") for (int ht = 0; ht < 4; ++ht)                          \
            acc[qi][ht] = mfma16(vs[ht], pf, acc[qi][ht]);                        \
    }                                                                             \
} while (0)

    bf16x8 k0[4], v0[4], k1[4], v1[4];
    LD_KV(k0, v0, 0);
    #pragma unroll 1
    for (int j = 0; j < jmax; j += 2) {
        LD_KV(k1, v1, j + 1);
        __builtin_amdgcn_sched_barrier(0);
        ATT_COMPUTE(k0, v0, j);
        if (j + 2 <= jmax) { LD_KV(k0, v0, j + 2); }
        __builtin_amdgcn_sched_barrier(0);
        ATT_COMPUTE(k1, v1, j + 1);
    }

    #pragma unroll
    for (int qi = 0; qi < 4; ++qi) {
        float rs = lsum[qi];
        rs += __shfl_xor(rs, 16, 64);
        rs += __shfl_xor(rs, 32, 64);
        const float inv_l = 1.0f / rs;
        // fragment-major Z write: rowg = (b*2048+q)>>4,
        // k = hn*64 + ht*16 + quad*4 (4 contiguous elems, 8B aligned)
        const int rowg = b*128 + (qbase >> 4) + qi;
        #pragma unroll
        for (int ht = 0; ht < 4; ++ht) {
            union { bf16x4 v; bf16 e[4]; } u;
            #pragma unroll
            for (int r = 0; r < 4; ++r) u.e[r] = __float2bfloat16(acc[qi][ht][r] * inv_l);
            const int k = hn*64 + ht*16 + quad*4;
            bf16* d = Zp + ((size_t)rowg*24 + (k>>5))*512
                         + (size_t)((((k>>3)&3)<<4) + l16)*8 + (k&7);
            *reinterpret_cast<bf16x4*>(d) = u.v;
        }
    }
#undef LD_KV
#undef ATT_COMPUTE
}

extern "C" void kernel_launch(void* const* d_in, const int* in_sizes, int n_in,
                              void* d_out, int out_size, void* d_ws, size_t ws_size,
                              hipStream_t stream)
{
    const float* x  = (const float*)d_in[0];
    const float* Wq = (const float*)d_in[1];
    const float* Wk = (const float*)d_in[2];
    const float* Wv = (const float*)d_in[3];
    const float* Wo = (const float*)d_in[4];
    const float* bq = (const float*)d_in[5];
    const float* bk = (const float*)d_in[6];
    const float* bv = (const float*)d_in[7];
    const float* bo = (const float*)d_in[8];
    float* out = (float*)d_out;

    char* ws = (char*)d_ws;
    size_t off = 0;
    auto alloc = [&](size_t bytes){ char* p = ws + off; off += (bytes + 255) & ~(size_t)255; return p; };
    bf16* xp   = (bf16*)alloc((size_t)BS*E_*2);     // packed fragment-major
    bf16* WTp  = (bf16*)alloc((size_t)3*NHD*E_*2);  // packed [Wq;Wk;Wv] B-frags
    bf16* WoTp = (bf16*)alloc((size_t)E_*NHD*2);    // packed Wo^T B-frags
    bf16* Qb   = (bf16*)alloc((size_t)BS*NHD*2);    // [B][N][S][H], pre-scaled log2e/8
    bf16* Kp   = (bf16*)alloc((size_t)BS*NHD*2);    // packed K frags (permuted)
    bf16* Vp   = (bf16*)alloc((size_t)BS*NHD*2);    // packed V^T frags
    bf16* Zp   = (bf16*)alloc((size_t)BS*NHD*2);    // fragment-major Z

    prep_kernel<<<4096, 256, 0, stream>>>(x, Wq, Wk, Wv, Wo, xp, WTp, WoTp);
    qkv_gemm_p<<<dim3(BS/128, 18), 256, 0, stream>>>(xp, WTp, bq, bk, bv, Qb, Kp, Vp);
    attn_kernel<<<768, 256, 0, stream>>>(Qb, Kp, Vp, Zp);
    out_gemm_p<<<dim3(BS/128, 8), 256, 0, stream>>>(Zp, WoTp, bo, out);
}